// Round 4
// baseline (405.242 us; speedup 1.0000x reference)
//
#include <hip/hip_runtime.h>
#include <hip/hip_bf16.h>

// Problem constants (from reference)
#define BB    16
#define LQ    64
#define LD    2048
#define HH    1024
#define DIM   128
#define MAXK  513          // LD/PF + 1 with PF=4
#define DGRID 512          // d-encode blocks (32768 / 64)
#define QGRID 16           // q-encode blocks (1024 / 64)
#define RSP   8            // q-row slices for simmax (8 rows each)

typedef __attribute__((ext_vector_type(8))) short short8;
typedef __attribute__((ext_vector_type(4))) float f32x4;

__device__ __forceinline__ float b2f(ushort u) {
    union { float f; unsigned int u32; } c; c.u32 = ((unsigned int)u) << 16; return c.f;
}
__device__ __forceinline__ ushort f2b_rn(float f) {
    unsigned int x = __float_as_uint(f);
    return (ushort)((x + 0x7fffu + ((x >> 16) & 1u)) >> 16);
}

// ---------------------------------------------------------------------------
// Fused prep: blocks 0..511 transpose+split W; blocks 512..527 compute kvals.
__global__ __launch_bounds__(256) void prep_kb_kernel(
    const float* __restrict__ W,
    const int*   __restrict__ d_mask,
    const int*   __restrict__ pf,
    ushort*      __restrict__ Wt_hi,
    ushort*      __restrict__ Wt_lo,
    int*         __restrict__ kvals)
{
    __shared__ int red[4];
    int bid = blockIdx.x, t = threadIdx.x;
    if (bid < 512) {
        int idx = bid * 256 + t;     // < H*DIM = 131072
        int h = idx >> 7;            // row in H
        int n = idx & 127;           // col in DIM
        float x = W[idx];
        ushort hi = f2b_rn(x);
        float r = x - b2f(hi);
        Wt_hi[n * HH + h] = hi;
        Wt_lo[n * HH + h] = f2b_rn(r);
    } else {
        int b = bid - 512;
        int lane = t & 63, wave = t >> 6;
        int s = 0;
        for (int i = t; i < LD; i += 256) s += (d_mask[b * LD + i] > 0) ? 1 : 0;
        #pragma unroll
        for (int m = 1; m < 64; m <<= 1) s += __shfl_xor(s, m);
        if (lane == 0) red[wave] = s;
        __syncthreads();
        if (t == 0) {
            int v = red[0] + red[1] + red[2] + red[3];
            if (v < 2) v = 2;
            int pfv = pf[0];
            if (pfv < 1 || pfv > LD) pfv = 4;   // defensive
            kvals[b] = v / pfv + 1;
        }
    }
}

// ---------------------------------------------------------------------------
// Encode + pooled scatter, barrier-free K-loop.
// Block = 512 threads = 8 waves: wave w -> 16 rows ((w&3)*16), K-half (w>>2).
// A: global->reg direct (per-lane rows, 16x128B segments/instr = full sectors).
// B: global->reg direct (0.5 MB, L1/L2 resident, shared by all blocks).
// NO LDS / NO barrier in the K-loop; one barrier to combine K-halves.
// Epilogue: bias + L2-normalize + mask; d-rows atomicAdd into cluster sums,
// q-rows stored to q_repr.
__global__ __launch_bounds__(512, 4) void encode_kernel(
    const float*  __restrict__ Xd,      // [32768][H]
    const float*  __restrict__ Xq,      // [1024][H]
    const ushort* __restrict__ Wt_hi,   // [DIM][H] bf16
    const ushort* __restrict__ Wt_lo,   // [DIM][H] bf16
    const float*  __restrict__ bias,    // [DIM]
    const int*    __restrict__ mask_d,  // [32768]
    const int*    __restrict__ mask_q,  // [1024]
    const int*    __restrict__ labels,  // [32768]
    const int*    __restrict__ kvals,   // [BB]
    float*        __restrict__ sums,    // [BB][MAXK][DIM]
    float*        __restrict__ q_repr)  // [1024][DIM]
{
    __shared__ float ldsc[64 * 132];    // K-half combine buffer (33 KB)

    const int bid = blockIdx.x;
    const bool isq = bid >= DGRID;
    const float* X = isq ? Xq : Xd;
    const long row0 = isq ? (long)(bid - DGRID) * 64 : (long)bid * 64;

    const int t = threadIdx.x;
    const int wave = t >> 6, lane = t & 63;
    const int m16 = lane & 15, quad = lane >> 4;
    const int w4 = wave & 3, kh = wave >> 2;

    // A: this lane's frag row, its quad's 8-float k-slice, in its K-half
    const float* ap = X + (row0 + w4 * 16 + m16) * HH + kh * 512 + quad * 8;
    // B: frag row ct*16+m16, same k-slice
    const ushort* bhp = Wt_hi + (long)m16 * HH + kh * 512 + quad * 8;
    const ushort* blp = Wt_lo + (long)m16 * HH + kh * 512 + quad * 8;

    f32x4 acc[8];
    #pragma unroll
    for (int j = 0; j < 8; ++j) acc[j] = (f32x4){0.f, 0.f, 0.f, 0.f};

    for (int c = 0; c < 16; ++c) {     // 16 chunks of K=32 per K-half
        float4 a0 = *(const float4*)(ap + c * 32);
        float4 a1 = *(const float4*)(ap + c * 32 + 4);

        short8 bh[8], bl[8];
        #pragma unroll
        for (int ct = 0; ct < 8; ++ct) {
            bh[ct] = *(const short8*)(bhp + (long)ct * 16 * HH + c * 32);
            bl[ct] = *(const short8*)(blp + (long)ct * 16 * HH + c * 32);
        }

        float av[8];
        *(float4*)(av) = a0; *(float4*)(av + 4) = a1;
        short8 ah, al;
        #pragma unroll
        for (int j = 0; j < 8; ++j) {
            unsigned int ux = __float_as_uint(av[j]);
            ah[j] = (short)(ux >> 16);
            float hif = __uint_as_float(ux & 0xffff0000u);
            al[j] = (short)(__float_as_uint(av[j] - hif) >> 16);
        }

        #pragma unroll
        for (int ct = 0; ct < 8; ++ct) {
            acc[ct] = __builtin_amdgcn_mfma_f32_16x16x32_bf16(ah, bh[ct], acc[ct], 0, 0, 0);
            acc[ct] = __builtin_amdgcn_mfma_f32_16x16x32_bf16(al, bh[ct], acc[ct], 0, 0, 0);
            acc[ct] = __builtin_amdgcn_mfma_f32_16x16x32_bf16(ah, bl[ct], acc[ct], 0, 0, 0);
        }
    }

    // combine K-halves through LDS (single barrier)
    if (kh == 0) {
        #pragma unroll
        for (int ct = 0; ct < 8; ++ct)
            #pragma unroll
            for (int r = 0; r < 4; ++r)
                ldsc[(w4 * 16 + quad * 4 + r) * 132 + ct * 16 + m16] = acc[ct][r];
    }
    __syncthreads();
    if (kh == 1) {
        float bia[8];
        #pragma unroll
        for (int ct = 0; ct < 8; ++ct) bia[ct] = bias[ct * 16 + m16];

        #pragma unroll
        for (int r = 0; r < 4; ++r) {
            long rowg = row0 + w4 * 16 + quad * 4 + r;
            float v[8];
            float ss = 0.f;
            #pragma unroll
            for (int ct = 0; ct < 8; ++ct) {
                v[ct] = acc[ct][r]
                      + ldsc[(w4 * 16 + quad * 4 + r) * 132 + ct * 16 + m16]
                      + bia[ct];
                ss += v[ct] * v[ct];
            }
            ss += __shfl_xor(ss, 1);
            ss += __shfl_xor(ss, 2);
            ss += __shfl_xor(ss, 4);
            ss += __shfl_xor(ss, 8);
            float scale = 1.0f / fmaxf(sqrtf(ss), 1e-12f);

            if (isq) {
                scale *= (float)mask_q[rowg];
                #pragma unroll
                for (int ct = 0; ct < 8; ++ct)
                    q_repr[rowg * DIM + ct * 16 + m16] = v[ct] * scale;
            } else {
                if (mask_d[rowg] > 0) {
                    int b = (int)(rowg >> 11);
                    int seg = labels[rowg] % kvals[b];
                    float* sp = sums + ((long)b * MAXK + seg) * DIM + m16;
                    #pragma unroll
                    for (int ct = 0; ct < 8; ++ct)
                        atomicAdd(sp + ct * 16, v[ct] * scale);
                }
            }
        }
    }
}

// ---------------------------------------------------------------------------
// Sim + max + sum, with inline cluster normalization:
//   normalize(mean) == normalize(sum)  (1/count cancels under L2-normalize)
// Block = (batch, 8-q-row slice). Each thread scans clusters t, t+256, ...
// Row maxes reduced in-block, masked, atomic-added into out[b].
__global__ __launch_bounds__(256) void simmax_kernel(
    const float* __restrict__ q_repr,   // [B][LQ][DIM]
    const float* __restrict__ sums,     // [B][MAXK][DIM] raw cluster sums
    const int*   __restrict__ kvals,
    const int*   __restrict__ q_mask,
    float*       __restrict__ out)      // [B] (pre-zeroed)
{
    __shared__ float qs[8 * 132];
    __shared__ float red[4][8];
    int b = blockIdx.x >> 3, rs = blockIdx.x & 7;
    int t = threadIdx.x, w = t >> 6, lane = t & 63;

    for (int i = t; i < 8 * DIM; i += 256) {
        int r = i >> 7, d = i & 127;
        qs[r * 132 + d] = q_repr[((long)b * LQ + rs * 8 + r) * DIM + d];
    }
    __syncthreads();

    int kb = kvals[b];
    float mx[8];
    #pragma unroll
    for (int r = 0; r < 8; ++r) mx[r] = -1e4f;

    for (int kk = t; kk < MAXK; kk += 256) {
        const float4* dp = (const float4*)(sums + ((long)b * MAXK + kk) * DIM);
        float dot[8];
        #pragma unroll
        for (int r = 0; r < 8; ++r) dot[r] = 0.f;
        float ss = 0.f;
        for (int d4 = 0; d4 < 32; ++d4) {
            float4 c = dp[d4];
            ss += c.x * c.x + c.y * c.y + c.z * c.z + c.w * c.w;
            #pragma unroll
            for (int r = 0; r < 8; ++r) {
                float4 q = *(const float4*)(&qs[r * 132 + d4 * 4]);
                dot[r] += q.x * c.x + q.y * c.y + q.z * c.z + q.w * c.w;
            }
        }
        float inv = (ss > 1e-24f) ? rsqrtf(ss) : 0.f;
        bool valid = kk < kb;
        #pragma unroll
        for (int r = 0; r < 8; ++r) {
            float sim = valid ? dot[r] * inv : -1e4f;
            mx[r] = fmaxf(mx[r], sim);
        }
    }

    #pragma unroll
    for (int r = 0; r < 8; ++r) {
        float v = mx[r];
        v = fmaxf(v, __shfl_xor(v, 1));
        v = fmaxf(v, __shfl_xor(v, 2));
        v = fmaxf(v, __shfl_xor(v, 4));
        v = fmaxf(v, __shfl_xor(v, 8));
        v = fmaxf(v, __shfl_xor(v, 16));
        v = fmaxf(v, __shfl_xor(v, 32));
        mx[r] = v;
    }
    if (lane == 0) {
        #pragma unroll
        for (int r = 0; r < 8; ++r) red[w][r] = mx[r];
    }
    __syncthreads();
    if (t < 8) {
        float m = fmaxf(fmaxf(red[0][t], red[1][t]), fmaxf(red[2][t], red[3][t]));
        m *= (float)q_mask[b * LQ + rs * 8 + t];
        atomicAdd(&out[b], m);
    }
}

// ---------------------------------------------------------------------------
extern "C" void kernel_launch(void* const* d_in, const int* in_sizes, int n_in,
                              void* d_out, int out_size, void* d_ws, size_t ws_size,
                              hipStream_t stream) {
    const float* q_hidden = (const float*)d_in[0];
    const float* d_hidden = (const float*)d_in[1];
    const float* W        = (const float*)d_in[2];
    const float* bias     = (const float*)d_in[3];
    const int*   q_mask   = (const int*)d_in[4];
    const int*   d_mask   = (const int*)d_in[5];
    const int*   labels   = (const int*)d_in[6];
    const int*   pf       = (const int*)d_in[7];

    float* ws     = (float*)d_ws;
    float* q_repr = ws;                                   // 131,072 f
    float* sums   = q_repr + (long)BB * LQ * DIM;         // 1,050,624 f
    int*   kvals  = (int*)(sums + (long)BB * MAXK * DIM); // 16
    ushort* Wt_hi = (ushort*)(kvals + 16);                // 131,072 bf16
    ushort* Wt_lo = Wt_hi + (long)DIM * HH;               // 131,072 bf16

    hipMemsetAsync(sums, 0, (size_t)BB * MAXK * DIM * sizeof(float), stream);
    hipMemsetAsync(d_out, 0, (size_t)out_size * sizeof(float), stream);

    prep_kb_kernel<<<512 + BB, 256, 0, stream>>>(W, d_mask, pf, Wt_hi, Wt_lo, kvals);
    encode_kernel<<<DGRID + QGRID, 512, 0, stream>>>(d_hidden, q_hidden, Wt_hi, Wt_lo,
                                                     bias, d_mask, q_mask, labels, kvals,
                                                     sums, q_repr);
    simmax_kernel<<<BB * RSP, 256, 0, stream>>>(q_repr, sums, kvals, q_mask, (float*)d_out);
}

// Round 5
// 291.457 us; speedup vs baseline: 1.3904x; 1.3904x over previous
//
#include <hip/hip_runtime.h>
#include <hip/hip_bf16.h>

// Problem constants (from reference)
#define BB    16
#define LQ    64
#define LD    2048
#define HH    1024
#define DIM   128
#define MAXK  513          // LD/PF + 1 with PF=4
#define DGRID 512          // d-encode blocks (32768 / 64)
#define QGRID 16           // q-encode blocks (1024 / 64)
#define RSP   16           // q-row slices for simmax (4 rows each)

typedef __attribute__((ext_vector_type(8))) short short8;
typedef __attribute__((ext_vector_type(4))) float f32x4;

__device__ __forceinline__ float b2f(ushort u) {
    union { float f; unsigned int u32; } c; c.u32 = ((unsigned int)u) << 16; return c.f;
}
__device__ __forceinline__ ushort f2b_rn(float f) {
    unsigned int x = __float_as_uint(f);
    return (ushort)((x + 0x7fffu + ((x >> 16) & 1u)) >> 16);
}

// async global->LDS, 16B per lane; LDS dest = wave-uniform base + lane*16
__device__ __forceinline__ void gld16(void* lds, const void* g) {
    __builtin_amdgcn_global_load_lds(
        (const __attribute__((address_space(1))) unsigned int*)g,
        (__attribute__((address_space(3))) unsigned int*)lds,
        16, 0, 0);
}

// ---------------------------------------------------------------------------
// Fused prep: blocks 0..511 transpose+split W; blocks 512..527 compute kvals.
__global__ __launch_bounds__(256) void prep_kb_kernel(
    const float* __restrict__ W,
    const int*   __restrict__ d_mask,
    const int*   __restrict__ pf,
    ushort*      __restrict__ Wt_hi,
    ushort*      __restrict__ Wt_lo,
    int*         __restrict__ kvals)
{
    __shared__ int red[4];
    int bid = blockIdx.x, t = threadIdx.x;
    if (bid < 512) {
        int idx = bid * 256 + t;     // < H*DIM = 131072
        int h = idx >> 7;            // row in H
        int n = idx & 127;           // col in DIM
        float x = W[idx];
        ushort hi = f2b_rn(x);
        float r = x - b2f(hi);
        Wt_hi[n * HH + h] = hi;
        Wt_lo[n * HH + h] = f2b_rn(r);
    } else {
        int b = bid - 512;
        int lane = t & 63, wave = t >> 6;
        int s = 0;
        for (int i = t; i < LD; i += 256) s += (d_mask[b * LD + i] > 0) ? 1 : 0;
        #pragma unroll
        for (int m = 1; m < 64; m <<= 1) s += __shfl_xor(s, m);
        if (lane == 0) red[wave] = s;
        __syncthreads();
        if (t == 0) {
            int v = red[0] + red[1] + red[2] + red[3];
            if (v < 2) v = 2;
            int pfv = pf[0];
            if (pfv < 1 || pfv > LD) pfv = 4;   // defensive
            kvals[b] = v / pfv + 1;
        }
    }
}

// ---------------------------------------------------------------------------
// Encode + fused pooled-scatter. m97-style K-loop:
//   64-row x 128-col tile, 256 threads (4 waves x 16 rows), BK=32,
//   double-buffered LDS filled ONLY via global_load_lds (16B),
//   one __syncthreads per chunk (prefetch distance = 1 chunk).
// LDS unit = 16B. Per buffer: A = units [0,512) : 64 rows x 8 slots (fp32),
//                             B = units [512,1536): 128 rows x 8 slots
//                                 (slots 0-3 = W_hi k-groups, 4-7 = W_lo).
// XOR swizzle: physical slot p holds logical slot g = p ^ (row & 7).
__global__ __launch_bounds__(256, 3) void encode_kernel(
    const float*  __restrict__ Xd,      // [32768][H]
    const float*  __restrict__ Xq,      // [1024][H]
    const ushort* __restrict__ Wt_hi,   // [DIM][H] bf16
    const ushort* __restrict__ Wt_lo,   // [DIM][H] bf16
    const float*  __restrict__ bias,    // [DIM]
    const int*    __restrict__ mask_d,  // [32768]
    const int*    __restrict__ mask_q,  // [1024]
    const int*    __restrict__ labels,  // [32768]
    const int*    __restrict__ kvals,   // [BB]
    float*        __restrict__ sums,    // [BB][MAXK][DIM]
    float*        __restrict__ q_repr)  // [1024][DIM]
{
    __shared__ __align__(16) uint4 buf[2][1536];   // 48 KB

    const int t = threadIdx.x;
    const int w = t >> 6, lane = t & 63;
    const int m16 = lane & 15, quad = lane >> 4;
    const int l8 = lane & 7, lr = lane >> 3;   // staging: phys slot, row-in-8
    const int g = l8 ^ lr;                     // staging: logical 16B slot

    const bool isq = blockIdx.x >= DGRID;
    const float* X = isq ? Xq : Xd;
    const long row0 = isq ? (long)(blockIdx.x - DGRID) * 64 : (long)blockIdx.x * 64;

    // staging global sources (per lane); advance by 32 elements per chunk
    const float* gA0 = X + (row0 + w * 16 + 0 + lr) * HH + g * 4;
    const float* gA1 = X + (row0 + w * 16 + 8 + lr) * HH + g * 4;
    const ushort* bsel = (g & 4) ? Wt_lo : Wt_hi;
    const ushort* gB0 = bsel + ((w * 4 + 0) * 8 + lr) * HH + (g & 3) * 8;
    const ushort* gB1 = bsel + ((w * 4 + 1) * 8 + lr) * HH + (g & 3) * 8;
    const ushort* gB2 = bsel + ((w * 4 + 2) * 8 + lr) * HH + (g & 3) * 8;
    const ushort* gB3 = bsel + ((w * 4 + 3) * 8 + lr) * HH + (g & 3) * 8;

    f32x4 acc[8];
    #pragma unroll
    for (int j = 0; j < 8; ++j) acc[j] = (f32x4){0.f, 0.f, 0.f, 0.f};

    // prologue: stage chunk 0 into buf[0]
    {
        gld16(&buf[0][(w * 2 + 0) * 64], gA0);
        gld16(&buf[0][(w * 2 + 1) * 64], gA1);
        gld16(&buf[0][512 + (w * 4 + 0) * 64], gB0);
        gld16(&buf[0][512 + (w * 4 + 1) * 64], gB1);
        gld16(&buf[0][512 + (w * 4 + 2) * 64], gB2);
        gld16(&buf[0][512 + (w * 4 + 3) * 64], gB3);
    }

    const int sw = m16 & 7;
    const int abase = (w * 16 + m16) * 8;

    for (int c = 0; c < 32; ++c) {
        __syncthreads();                 // waits vmcnt: buf[c&1] staged
        const int cur = c & 1;

        if (c < 31) {                    // prefetch chunk c+1 into other buffer
            const int nxt = cur ^ 1;
            const int ko = (c + 1) * 32;
            gld16(&buf[nxt][(w * 2 + 0) * 64], gA0 + ko);
            gld16(&buf[nxt][(w * 2 + 1) * 64], gA1 + ko);
            gld16(&buf[nxt][512 + (w * 4 + 0) * 64], gB0 + ko);
            gld16(&buf[nxt][512 + (w * 4 + 1) * 64], gB1 + ko);
            gld16(&buf[nxt][512 + (w * 4 + 2) * 64], gB2 + ko);
            gld16(&buf[nxt][512 + (w * 4 + 3) * 64], gB3 + ko);
        }

        // A fragment: rows w*16+m16, logical slots 2q, 2q+1
        float4 va0 = *(const float4*)&buf[cur][abase + ((2 * quad) ^ sw)];
        float4 va1 = *(const float4*)&buf[cur][abase + ((2 * quad + 1) ^ sw)];
        float av[8];
        *(float4*)(av) = va0; *(float4*)(av + 4) = va1;
        short8 ah, al;
        #pragma unroll
        for (int j = 0; j < 8; ++j) {
            unsigned int ux = __float_as_uint(av[j]);
            ah[j] = (short)(ux >> 16);
            float hif = __uint_as_float(ux & 0xffff0000u);
            al[j] = (short)(__float_as_uint(av[j] - hif) >> 16);
        }

        #pragma unroll
        for (int ct = 0; ct < 8; ++ct) {
            const int bbase = 512 + (ct * 16 + m16) * 8;
            short8 bh = *(const short8*)&buf[cur][bbase + (quad ^ sw)];
            short8 bl = *(const short8*)&buf[cur][bbase + ((quad + 4) ^ sw)];
            acc[ct] = __builtin_amdgcn_mfma_f32_16x16x32_bf16(ah, bh, acc[ct], 0, 0, 0);
            acc[ct] = __builtin_amdgcn_mfma_f32_16x16x32_bf16(al, bh, acc[ct], 0, 0, 0);
            acc[ct] = __builtin_amdgcn_mfma_f32_16x16x32_bf16(ah, bl, acc[ct], 0, 0, 0);
        }
    }

    // epilogue: bias + L2-normalize + mask; d-rows scatter, q-rows store
    float bia[8];
    #pragma unroll
    for (int ct = 0; ct < 8; ++ct) bia[ct] = bias[ct * 16 + m16];

    #pragma unroll
    for (int r = 0; r < 4; ++r) {
        long rowg = row0 + w * 16 + quad * 4 + r;
        float v[8];
        float ss = 0.f;
        #pragma unroll
        for (int ct = 0; ct < 8; ++ct) {
            v[ct] = acc[ct][r] + bia[ct];
            ss += v[ct] * v[ct];
        }
        ss += __shfl_xor(ss, 1);
        ss += __shfl_xor(ss, 2);
        ss += __shfl_xor(ss, 4);
        ss += __shfl_xor(ss, 8);
        float scale = 1.0f / fmaxf(sqrtf(ss), 1e-12f);

        if (isq) {
            scale *= (float)mask_q[rowg];
            #pragma unroll
            for (int ct = 0; ct < 8; ++ct)
                q_repr[rowg * DIM + ct * 16 + m16] = v[ct] * scale;
        } else {
            if (mask_d[rowg] > 0) {
                int b = (int)(rowg >> 11);
                int seg = labels[rowg] % kvals[b];
                float* sp = sums + ((long)b * MAXK + seg) * DIM + m16;
                #pragma unroll
                for (int ct = 0; ct < 8; ++ct)
                    atomicAdd(sp + ct * 16, v[ct] * scale);
            }
        }
    }
}

// ---------------------------------------------------------------------------
// Sim + max + sum, inline cluster normalization (normalize(mean)==normalize(sum)).
// Block = (batch, 4-q-row slice) -> 256 blocks. Thread scans clusters t, t+256.
__global__ __launch_bounds__(256) void simmax_kernel(
    const float* __restrict__ q_repr,   // [B][LQ][DIM]
    const float* __restrict__ sums,     // [B][MAXK][DIM] raw cluster sums
    const int*   __restrict__ kvals,
    const int*   __restrict__ q_mask,
    float*       __restrict__ out)      // [B] (pre-zeroed)
{
    __shared__ float qs[4 * 132];
    __shared__ float red[4][4];
    int b = blockIdx.x >> 4, rs = blockIdx.x & 15;
    int t = threadIdx.x, w = t >> 6, lane = t & 63;

    for (int i = t; i < 4 * DIM; i += 256) {
        int r = i >> 7, d = i & 127;
        qs[r * 132 + d] = q_repr[((long)b * LQ + rs * 4 + r) * DIM + d];
    }
    __syncthreads();

    int kb = kvals[b];
    float mx[4];
    #pragma unroll
    for (int r = 0; r < 4; ++r) mx[r] = -1e4f;

    for (int kk = t; kk < MAXK; kk += 256) {
        const float4* dp = (const float4*)(sums + ((long)b * MAXK + kk) * DIM);
        float dot[4];
        #pragma unroll
        for (int r = 0; r < 4; ++r) dot[r] = 0.f;
        float ss = 0.f;
        for (int d4 = 0; d4 < 32; ++d4) {
            float4 c = dp[d4];
            ss += c.x * c.x + c.y * c.y + c.z * c.z + c.w * c.w;
            #pragma unroll
            for (int r = 0; r < 4; ++r) {
                float4 q = *(const float4*)(&qs[r * 132 + d4 * 4]);
                dot[r] += q.x * c.x + q.y * c.y + q.z * c.z + q.w * c.w;
            }
        }
        float inv = (ss > 1e-24f) ? rsqrtf(ss) : 0.f;
        bool valid = kk < kb;
        #pragma unroll
        for (int r = 0; r < 4; ++r) {
            float sim = valid ? dot[r] * inv : -1e4f;
            mx[r] = fmaxf(mx[r], sim);
        }
    }

    #pragma unroll
    for (int r = 0; r < 4; ++r) {
        float v = mx[r];
        v = fmaxf(v, __shfl_xor(v, 1));
        v = fmaxf(v, __shfl_xor(v, 2));
        v = fmaxf(v, __shfl_xor(v, 4));
        v = fmaxf(v, __shfl_xor(v, 8));
        v = fmaxf(v, __shfl_xor(v, 16));
        v = fmaxf(v, __shfl_xor(v, 32));
        mx[r] = v;
    }
    if (lane == 0) {
        #pragma unroll
        for (int r = 0; r < 4; ++r) red[w][r] = mx[r];
    }
    __syncthreads();
    if (t < 4) {
        float m = fmaxf(fmaxf(red[0][t], red[1][t]), fmaxf(red[2][t], red[3][t]));
        m *= (float)q_mask[b * LQ + rs * 4 + t];
        atomicAdd(&out[b], m);
    }
}

// ---------------------------------------------------------------------------
extern "C" void kernel_launch(void* const* d_in, const int* in_sizes, int n_in,
                              void* d_out, int out_size, void* d_ws, size_t ws_size,
                              hipStream_t stream) {
    const float* q_hidden = (const float*)d_in[0];
    const float* d_hidden = (const float*)d_in[1];
    const float* W        = (const float*)d_in[2];
    const float* bias     = (const float*)d_in[3];
    const int*   q_mask   = (const int*)d_in[4];
    const int*   d_mask   = (const int*)d_in[5];
    const int*   labels   = (const int*)d_in[6];
    const int*   pf       = (const int*)d_in[7];

    float* ws     = (float*)d_ws;
    float* q_repr = ws;                                   // 131,072 f
    float* sums   = q_repr + (long)BB * LQ * DIM;         // 1,050,624 f
    int*   kvals  = (int*)(sums + (long)BB * MAXK * DIM); // 16
    ushort* Wt_hi = (ushort*)(kvals + 16);                // 131,072 bf16
    ushort* Wt_lo = Wt_hi + (long)DIM * HH;               // 131,072 bf16

    hipMemsetAsync(sums, 0, (size_t)BB * MAXK * DIM * sizeof(float), stream);
    hipMemsetAsync(d_out, 0, (size_t)out_size * sizeof(float), stream);

    prep_kb_kernel<<<512 + BB, 256, 0, stream>>>(W, d_mask, pf, Wt_hi, Wt_lo, kvals);
    encode_kernel<<<DGRID + QGRID, 256, 0, stream>>>(d_hidden, q_hidden, Wt_hi, Wt_lo,
                                                     bias, d_mask, q_mask, labels, kvals,
                                                     sums, q_repr);
    simmax_kernel<<<BB * RSP, 256, 0, stream>>>(q_repr, sums, kvals, q_mask, (float*)d_out);
}

// Round 6
// 256.905 us; speedup vs baseline: 1.5774x; 1.1345x over previous
//
#include <hip/hip_runtime.h>
#include <hip/hip_bf16.h>

// Problem constants (from reference)
#define BB    16
#define LQ    64
#define LD    2048
#define HH    1024
#define DIM   128
#define MAXK  513          // LD/PF + 1 with PF=4
#define SCH   9            // ceil(513/64) cluster chunks for simmax
#define DGRID 1024         // d-encode blocks (32768 / 32)
#define QGRID 32           // q-encode blocks (1024 / 32)

typedef __attribute__((ext_vector_type(8))) short short8;
typedef __attribute__((ext_vector_type(4))) float f32x4;

__device__ __forceinline__ float b2f(ushort u) {
    union { float f; unsigned int u32; } c; c.u32 = ((unsigned int)u) << 16; return c.f;
}
__device__ __forceinline__ ushort f2b_rn(float f) {
    unsigned int x = __float_as_uint(f);
    return (ushort)((x + 0x7fffu + ((x >> 16) & 1u)) >> 16);
}

// async global->LDS, 16B/lane; LDS dest = wave-uniform base + lane*16
__device__ __forceinline__ void gld16(void* lds, const void* g) {
    __builtin_amdgcn_global_load_lds(
        (const __attribute__((address_space(1))) unsigned int*)g,
        (__attribute__((address_space(3))) unsigned int*)lds,
        16, 0, 0);
}

// ---------------------------------------------------------------------------
// Fused prep: blocks 0..511 transpose+round W -> Wt bf16; 512..527 kvals.
__global__ __launch_bounds__(256) void prep_kb_kernel(
    const float* __restrict__ W,
    const int*   __restrict__ d_mask,
    const int*   __restrict__ pf,
    ushort*      __restrict__ Wt,
    int*         __restrict__ kvals)
{
    __shared__ int red[4];
    int bid = blockIdx.x, t = threadIdx.x;
    if (bid < 512) {
        int idx = bid * 256 + t;     // < H*DIM = 131072
        int h = idx >> 7;            // row in H
        int n = idx & 127;           // col in DIM
        Wt[n * HH + h] = f2b_rn(W[idx]);
    } else {
        int b = bid - 512;
        int lane = t & 63, wave = t >> 6;
        int s = 0;
        for (int i = t; i < LD; i += 256) s += (d_mask[b * LD + i] > 0) ? 1 : 0;
        #pragma unroll
        for (int m = 1; m < 64; m <<= 1) s += __shfl_xor(s, m);
        if (lane == 0) red[wave] = s;
        __syncthreads();
        if (t == 0) {
            int v = red[0] + red[1] + red[2] + red[3];
            if (v < 2) v = 2;
            int pfv = pf[0];
            if (pfv < 1 || pfv > LD) pfv = 4;   // defensive
            kvals[b] = v / pfv + 1;
        }
    }
}

// ---------------------------------------------------------------------------
// Encode + fused pooled-scatter.
// 32-row x 128-col tile, 256 threads = 4 waves: wave w -> rows (w&1)*16,
// ct-group (w>>1)*4. BK=32, double-buffered LDS filled only via gld16,
// one barrier/chunk. 2 MFMA passes: A split hi+lo (exact), W rounded bf16.
// LDS units of 16B/buffer: A = [0,256): 32 rows x 8 units (fp32, xor row&7);
// B = [256,768): 128 rows x 4 units (bf16, xor (row>>2)&3).
__global__ __launch_bounds__(256, 4) void encode_kernel(
    const float*  __restrict__ Xd,      // [32768][H]
    const float*  __restrict__ Xq,      // [1024][H]
    const ushort* __restrict__ Wt,      // [DIM][H] bf16 rounded
    const float*  __restrict__ bias,    // [DIM]
    const int*    __restrict__ mask_d,  // [32768]
    const int*    __restrict__ mask_q,  // [1024]
    const int*    __restrict__ labels,  // [32768]
    const int*    __restrict__ kvals,   // [BB]
    float*        __restrict__ sums,    // [BB][MAXK][DIM]
    float*        __restrict__ q_repr)  // [1024][DIM]
{
    __shared__ __align__(16) uint4 buf[2][768];   // 24 KB
    __shared__ float ssh[32][2];

    const int bid = blockIdx.x;
    const bool isq = bid >= DGRID;
    const float* X = isq ? Xq : Xd;
    const long row0 = isq ? (long)(bid - DGRID) * 32 : (long)bid * 32;

    const int t = threadIdx.x;
    const int w = t >> 6, lane = t & 63;
    const int m16 = lane & 15, quad = lane >> 4;
    const int rh = w & 1, ch = w >> 1;

    // staging sources (per lane), advance 32 elements per chunk
    const float*  gA  = X + (row0 + w * 8 + (lane >> 3)) * HH
                          + (((lane & 7) ^ ((lane >> 3) & 7)) * 4);
    const ushort* gB0 = Wt + (long)(w * 32 + (lane >> 2)) * HH
                           + (((lane & 3) ^ ((lane >> 4) & 3)) * 8);
    const ushort* gB1 = gB0 + 16 * HH;

    f32x4 acc[4];
    #pragma unroll
    for (int j = 0; j < 4; ++j) acc[j] = (f32x4){0.f, 0.f, 0.f, 0.f};

    // prologue: stage chunk 0
    gld16(&buf[0][w * 64], gA);
    gld16(&buf[0][256 + w * 128], gB0);
    gld16(&buf[0][256 + w * 128 + 64], gB1);

    const int sw = m16 & 7;
    const int bsw = m16 >> 2;
    const int au = (rh * 16 + m16) * 8;

    for (int c = 0; c < 32; ++c) {
        __syncthreads();                 // drains vmcnt: buf[c&1] staged
        const int cur = c & 1;

        if (c < 31) {                    // prefetch c+1 into other buffer
            const int nxt = cur ^ 1;
            const int ko = (c + 1) * 32;
            gld16(&buf[nxt][w * 64], gA + ko);
            gld16(&buf[nxt][256 + w * 128], gB0 + ko);
            gld16(&buf[nxt][256 + w * 128 + 64], gB1 + ko);
        }

        float4 va0 = *(const float4*)&buf[cur][au + ((2 * quad) ^ sw)];
        float4 va1 = *(const float4*)&buf[cur][au + ((2 * quad + 1) ^ sw)];
        float av[8];
        *(float4*)(av) = va0; *(float4*)(av + 4) = va1;
        short8 ah, al;
        #pragma unroll
        for (int j = 0; j < 8; ++j) {
            unsigned int ux = __float_as_uint(av[j]);
            ah[j] = (short)(ux >> 16);
            float hif = __uint_as_float(ux & 0xffff0000u);
            al[j] = (short)(__float_as_uint(av[j] - hif) >> 16);
        }

        #pragma unroll
        for (int cti = 0; cti < 4; ++cti) {
            const int ct = ch * 4 + cti;
            short8 bf = *(const short8*)&buf[cur][256 + (ct * 16 + m16) * 4 + (quad ^ bsw)];
            acc[cti] = __builtin_amdgcn_mfma_f32_16x16x32_bf16(ah, bf, acc[cti], 0, 0, 0);
            acc[cti] = __builtin_amdgcn_mfma_f32_16x16x32_bf16(al, bf, acc[cti], 0, 0, 0);
        }
    }

    // epilogue: bias, cross-wave row norm (cols split across ch), mask, scatter
    float bia[4];
    #pragma unroll
    for (int cti = 0; cti < 4; ++cti) bia[cti] = bias[(ch * 4 + cti) * 16 + m16];

    float vv[4][4];
    float ssp[4] = {0.f, 0.f, 0.f, 0.f};
    #pragma unroll
    for (int cti = 0; cti < 4; ++cti)
        #pragma unroll
        for (int r = 0; r < 4; ++r) {
            vv[cti][r] = acc[cti][r] + bia[cti];
            ssp[r] += vv[cti][r] * vv[cti][r];
        }
    #pragma unroll
    for (int r = 0; r < 4; ++r) {
        ssp[r] += __shfl_xor(ssp[r], 1);
        ssp[r] += __shfl_xor(ssp[r], 2);
        ssp[r] += __shfl_xor(ssp[r], 4);
        ssp[r] += __shfl_xor(ssp[r], 8);
    }
    if (m16 == 0) {
        #pragma unroll
        for (int r = 0; r < 4; ++r) ssh[rh * 16 + quad * 4 + r][ch] = ssp[r];
    }
    __syncthreads();

    #pragma unroll
    for (int r = 0; r < 4; ++r) {
        int rowl = rh * 16 + quad * 4 + r;
        long rowg = row0 + rowl;
        float ss = ssh[rowl][0] + ssh[rowl][1];
        float scale = 1.0f / fmaxf(sqrtf(ss), 1e-12f);
        if (isq) {
            scale *= (float)mask_q[rowg];
            #pragma unroll
            for (int cti = 0; cti < 4; ++cti)
                q_repr[rowg * DIM + (ch * 4 + cti) * 16 + m16] = vv[cti][r] * scale;
        } else if (mask_d[rowg] > 0) {
            int b = (int)(rowg >> 11);
            int seg = labels[rowg] % kvals[b];
            float* sp = sums + ((long)b * MAXK + seg) * DIM + m16;
            #pragma unroll
            for (int cti = 0; cti < 4; ++cti)
                atomicAdd(sp + (ch * 4 + cti) * 16, vv[cti][r] * scale);
        }
    }
}

// ---------------------------------------------------------------------------
// Sim via MFMA: block = (b, 64-cluster chunk). Stage Q (split bf16) and C
// (rounded bf16) in LDS, 16x16x32 MFMA over K=DIM=128, normalize(sum) trick
// via per-cluster rsqrt, shuffle-max over clusters -> pmax[b][chunk][64].
__global__ __launch_bounds__(256) void simmax_kernel(
    const float* __restrict__ q_repr,   // [B][LQ][DIM]
    const float* __restrict__ sums,     // [B][MAXK][DIM] raw cluster sums
    const int*   __restrict__ kvals,
    float*       __restrict__ pmax)     // [B][SCH][64]
{
    __shared__ __align__(16) ushort Qh[64 * 136];
    __shared__ __align__(16) ushort Ql[64 * 136];
    __shared__ __align__(16) ushort Ch[64 * 136];
    __shared__ float cn[64];

    int b = blockIdx.x / SCH, chunk = blockIdx.x % SCH;
    int t = threadIdx.x, w = t >> 6, lane = t & 63;
    int m16 = lane & 15, quad = lane >> 4;

    // stage Q (64 rows x 128), split hi/lo
    #pragma unroll
    for (int i = 0; i < 8; ++i) {
        int flat = i * 256 + t;          // float4 index
        int row = flat >> 5, c4 = flat & 31;
        float4 v = *(const float4*)(q_repr + ((long)b * LQ + row) * DIM + c4 * 4);
        float x[4]; *(float4*)x = v;
        ushort4 h, l;
        ushort* hp = (ushort*)&h; ushort* lp = (ushort*)&l;
        #pragma unroll
        for (int j = 0; j < 4; ++j) {
            unsigned int ux = __float_as_uint(x[j]);
            hp[j] = (ushort)(ux >> 16);
            lp[j] = f2b_rn(x[j] - __uint_as_float(ux & 0xffff0000u));
        }
        *(ushort4*)&Qh[row * 136 + c4 * 4] = h;
        *(ushort4*)&Ql[row * 136 + c4 * 4] = l;
    }
    // stage C (64 clusters x 128), rounded bf16
    #pragma unroll
    for (int i = 0; i < 8; ++i) {
        int flat = i * 256 + t;
        int row = flat >> 5, c4 = flat & 31;
        int kk = chunk * 64 + row;
        float4 v = (kk < MAXK)
            ? *(const float4*)(sums + ((long)b * MAXK + kk) * DIM + c4 * 4)
            : make_float4(0.f, 0.f, 0.f, 0.f);
        ushort4 h; ushort* hp = (ushort*)&h;
        hp[0] = f2b_rn(v.x); hp[1] = f2b_rn(v.y);
        hp[2] = f2b_rn(v.z); hp[3] = f2b_rn(v.w);
        *(ushort4*)&Ch[row * 136 + c4 * 4] = h;
    }
    __syncthreads();

    // per-cluster inv-norms from staged C (quad-split over d, shuffle-combine)
    {
        int c = w * 16 + m16;
        float ssv = 0.f;
        #pragma unroll
        for (int j = 0; j < 16; ++j) {
            unsigned int u = *(const unsigned int*)&Ch[c * 136 + quad * 32 + j * 2];
            float x0 = b2f((ushort)u), x1 = b2f((ushort)(u >> 16));
            ssv += x0 * x0 + x1 * x1;
        }
        ssv += __shfl_xor(ssv, 16);
        ssv += __shfl_xor(ssv, 32);
        if (quad == 0) cn[c] = (ssv > 1e-24f) ? rsqrtf(ssv) : 0.f;
    }
    __syncthreads();

    // MFMA: wave w -> q rows [w*16, w*16+16), all 64 clusters (4 ct tiles)
    f32x4 acc[4];
    #pragma unroll
    for (int j = 0; j < 4; ++j) acc[j] = (f32x4){0.f, 0.f, 0.f, 0.f};

    #pragma unroll
    for (int kc = 0; kc < 4; ++kc) {
        short8 qh = *(const short8*)&Qh[(w * 16 + m16) * 136 + kc * 32 + quad * 8];
        short8 ql = *(const short8*)&Ql[(w * 16 + m16) * 136 + kc * 32 + quad * 8];
        #pragma unroll
        for (int ct = 0; ct < 4; ++ct) {
            short8 cf = *(const short8*)&Ch[(ct * 16 + m16) * 136 + kc * 32 + quad * 8];
            acc[ct] = __builtin_amdgcn_mfma_f32_16x16x32_bf16(qh, cf, acc[ct], 0, 0, 0);
            acc[ct] = __builtin_amdgcn_mfma_f32_16x16x32_bf16(ql, cf, acc[ct], 0, 0, 0);
        }
    }

    int kb = kvals[b];
    #pragma unroll
    for (int r = 0; r < 4; ++r) {
        float mx = -1e4f;
        #pragma unroll
        for (int ct = 0; ct < 4; ++ct) {
            int cl = chunk * 64 + ct * 16 + m16;
            float sim = acc[ct][r] * cn[ct * 16 + m16];
            mx = fmaxf(mx, (cl < kb) ? sim : -1e4f);
        }
        mx = fmaxf(mx, __shfl_xor(mx, 1));
        mx = fmaxf(mx, __shfl_xor(mx, 2));
        mx = fmaxf(mx, __shfl_xor(mx, 4));
        mx = fmaxf(mx, __shfl_xor(mx, 8));
        if (m16 == 0)
            pmax[((long)b * SCH + chunk) * 64 + w * 16 + quad * 4 + r] = mx;
    }
}

// ---------------------------------------------------------------------------
// Final: per batch, max over chunks, *q_mask, sum over rows -> out[b]
__global__ __launch_bounds__(64) void final_kernel(
    const float* __restrict__ pmax,
    const int*   __restrict__ q_mask,
    float*       __restrict__ out)
{
    int b = blockIdx.x, r = threadIdx.x;
    float m = -3e38f;
    #pragma unroll
    for (int c = 0; c < SCH; ++c)
        m = fmaxf(m, pmax[((long)b * SCH + c) * 64 + r]);
    m *= (float)q_mask[b * LQ + r];
    #pragma unroll
    for (int sh = 1; sh < 64; sh <<= 1) m += __shfl_xor(m, sh);
    if (r == 0) out[b] = m;
}

// ---------------------------------------------------------------------------
extern "C" void kernel_launch(void* const* d_in, const int* in_sizes, int n_in,
                              void* d_out, int out_size, void* d_ws, size_t ws_size,
                              hipStream_t stream) {
    const float* q_hidden = (const float*)d_in[0];
    const float* d_hidden = (const float*)d_in[1];
    const float* W        = (const float*)d_in[2];
    const float* bias     = (const float*)d_in[3];
    const int*   q_mask   = (const int*)d_in[4];
    const int*   d_mask   = (const int*)d_in[5];
    const int*   labels   = (const int*)d_in[6];
    const int*   pf       = (const int*)d_in[7];

    float* ws     = (float*)d_ws;
    float* q_repr = ws;                                   // 131,072 f
    float* sums   = q_repr + (long)BB * LQ * DIM;         // 1,050,624 f
    float* pmaxb  = sums + (long)BB * MAXK * DIM;         // 16*9*64 = 9,216 f
    int*   kvals  = (int*)(pmaxb + BB * SCH * 64);        // 16
    ushort* Wt    = (ushort*)(kvals + 16);                // 131,072 bf16

    hipMemsetAsync(sums, 0, (size_t)BB * MAXK * DIM * sizeof(float), stream);

    prep_kb_kernel<<<512 + BB, 256, 0, stream>>>(W, d_mask, pf, Wt, kvals);
    encode_kernel<<<DGRID + QGRID, 256, 0, stream>>>(d_hidden, q_hidden, Wt, bias,
                                                     d_mask, q_mask, labels, kvals,
                                                     sums, q_repr);
    simmax_kernel<<<BB * SCH, 256, 0, stream>>>(q_repr, sums, kvals, pmaxb);
    final_kernel<<<BB, 64, 0, stream>>>(pmaxb, q_mask, (float*)d_out);
}